// Round 1
// baseline (314.990 us; speedup 1.0000x reference)
//
#include <hip/hip_runtime.h>

#define DIM 64
#define NHEADS 8
#define NPOS 2048
#define PADW 3

typedef float f32x4 __attribute__((ext_vector_type(4)));

// Taylor coefficients 1/j!
#define C1 1.0f
#define C2 0.5f
#define C3 (1.0f / 6.0f)
#define C4 (1.0f / 24.0f)
#define C5 (1.0f / 120.0f)
#define C6 (1.0f / 720.0f)
#define C7 (1.0f / 5040.0f)
#define C8 (1.0f / 40320.0f)

__device__ __forceinline__ f32x4 ld4(const float* p) { return *reinterpret_cast<const f32x4*>(p); }
__device__ __forceinline__ void st4(float* p, f32x4 v) { *reinterpret_cast<f32x4*>(p) = v; }
__device__ __forceinline__ void tzero(float (&a)[4][4]) {
#pragma unroll
  for (int i = 0; i < 4; ++i)
#pragma unroll
    for (int j = 0; j < 4; ++j) a[i][j] = 0.0f;
}
__device__ __forceinline__ void tfma(float (&a)[4][4], const f32x4 x, const f32x4 y) {
#pragma unroll
  for (int i = 0; i < 4; ++i)
#pragma unroll
    for (int j = 0; j < 4; ++j) a[i][j] = fmaf(x[i], y[j], a[i][j]);
}

// Prologue v2: powers[b] = expm(k*A) where A = (U_m - U_m^T)/64, k = b>>3 (h = b&7,
// head m = 8+h; slot 88 = sos = expm(A_16)). Uses B^k = expm(kA) (A commutes with
// itself) -- no binary exponentiation. Antisymmetry gives (M^j)^T = (-1)^j M^j, so
// every needed transpose is a free sign flip.
//
// Matmul primitive: prim(X,Y) = X^T * Y with both operands read along ROWS:
// thread (256/block) owns 4x4 output tile; per k: two ds_read_b128
// (X[k][r0..r0+3], Y[k][c0..c0+3]), 16 FMAs. Conflict-free, 4x fewer LDS
// issues than the previous 1024-thread row-band scheme.
//
// Schedule (M = (k/4)A, s=2 scaling, Paterson-Stockmeyer K=8):
//   P0 : Ms  = M                                   -> b0
//   P1 : M2  = -prim(Ms,Ms)      ( = M^2 )         -> b1
//   P23: M3  = -prim(Ms,M2), M4 = prim(M2,M2)      -> b2, b3   (fused, shared loads)
//   P4 : E   = low(M) + M^4*Q(M),  Et = E(-M)=E^T  -> b0, b1   (dual acc, Q on the fly)
//   P5 : E2  = prim(Et,E), E2t = prim(E,Et)        -> b2, b3   (fused)
//   P6 : E4  = prim(E2t,E2) = expm(kA)             -> global
// Error: theta = k*||A||_2/4 <= ~0.31 (k<=10, ||A||_2 ~ 2*sigma*sqrt(64) ~ 0.10),
// Taylor-8 remainder theta^9/9! ~ 5e-11 << fp32 eps.
__global__ __launch_bounds__(256, 1) void prologue_kernel(const float* __restrict__ U,
                                                          float* __restrict__ powers) {
  __shared__ __align__(16) float b0[4096];
  __shared__ __align__(16) float b1[4096];
  __shared__ __align__(16) float b2[4096];
  __shared__ __align__(16) float b3[4096];
  const int t = threadIdx.x;
  const int b = blockIdx.x;
  const bool sos = (b == 88);
  const int kp = sos ? 1 : (b >> 3);
  float* __restrict__ dst = powers + (size_t)b * 4096;

  if (kp == 0) {  // B^0 = I
    for (int i = t; i < 4096; i += 256) dst[i] = ((i >> 6) == (i & 63)) ? 1.0f : 0.0f;
    return;
  }

  const int m = sos ? 16 : (NHEADS + (b & 7));
  const float* __restrict__ Um = U + (size_t)m * 4096;
  const float scale = (float)kp * (1.0f / 256.0f);  // k/4 * 1/64

  const int r0 = ((t >> 4) & 15) << 2;  // tile rows r0..r0+3
  const int c0 = (t & 15) << 2;         // tile cols c0..c0+3

  // ---- P0: Ms = scale * (U - U^T) ----
  {
    f32x4 ur[4], uc[4];
#pragma unroll
    for (int i = 0; i < 4; ++i) ur[i] = ld4(&Um[(r0 + i) * 64 + c0]);
#pragma unroll
    for (int j = 0; j < 4; ++j) uc[j] = ld4(&Um[(c0 + j) * 64 + r0]);
#pragma unroll
    for (int i = 0; i < 4; ++i) {
      f32x4 v;
#pragma unroll
      for (int j = 0; j < 4; ++j) v[j] = scale * (ur[i][j] - uc[j][i]);
      st4(&b0[(r0 + i) * 64 + c0], v);
    }
  }
  __syncthreads();

  // ---- P1: M2 = M*M = -(Ms^T Ms) ----
  {
    float a[4][4];
    tzero(a);
#pragma unroll 4
    for (int k = 0; k < 64; ++k) tfma(a, ld4(&b0[k * 64 + r0]), ld4(&b0[k * 64 + c0]));
#pragma unroll
    for (int i = 0; i < 4; ++i) {
      f32x4 v;
#pragma unroll
      for (int j = 0; j < 4; ++j) v[j] = -a[i][j];
      st4(&b1[(r0 + i) * 64 + c0], v);
    }
  }
  __syncthreads();

  // ---- P23 (fused): M3 = M*M2 = -(Ms^T M2);  M4 = M2*M2 = (M2^T M2) ----
  {
    float a3[4][4], a4[4][4];
    tzero(a3);
    tzero(a4);
#pragma unroll 4
    for (int k = 0; k < 64; ++k) {
      const f32x4 msr = ld4(&b0[k * 64 + r0]);
      const f32x4 m2r = ld4(&b1[k * 64 + r0]);
      const f32x4 m2c = ld4(&b1[k * 64 + c0]);
      tfma(a3, msr, m2c);
      tfma(a4, m2r, m2c);
    }
#pragma unroll
    for (int i = 0; i < 4; ++i) {
      f32x4 v3, v4;
#pragma unroll
      for (int j = 0; j < 4; ++j) {
        v3[j] = -a3[i][j];
        v4[j] = a4[i][j];
      }
      st4(&b2[(r0 + i) * 64 + c0], v3);
      st4(&b3[(r0 + i) * 64 + c0], v4);
    }
  }
  __syncthreads();

  // ---- P4 (dual): tails M^4*Q(+-M) with Q = C5*M + C6*M2 + C7*M3 + C8*M4 built on
  // the fly; then E = low(M)+tail, Et = low(-M)+tail' written in place over b0/b1.
  {
    float aE[4][4], aO[4][4];
    tzero(aE);
    tzero(aO);
#pragma unroll 2
    for (int k = 0; k < 64; ++k) {
      const f32x4 xv = ld4(&b3[k * 64 + r0]);   // M4 row chunk (M4^T = M4)
      const f32x4 msv = ld4(&b0[k * 64 + c0]);
      const f32x4 m2v = ld4(&b1[k * 64 + c0]);
      const f32x4 m3v = ld4(&b2[k * 64 + c0]);
      const f32x4 m4v = ld4(&b3[k * 64 + c0]);
      f32x4 ev, ov, yv, yw;
#pragma unroll
      for (int j = 0; j < 4; ++j) {
        ev[j] = fmaf(C8, m4v[j], C6 * m2v[j]);  // even part of Q
        ov[j] = fmaf(C7, m3v[j], C5 * msv[j]);  // odd part of Q
        yv[j] = ev[j] + ov[j];                  // Q(M)
        yw[j] = ev[j] - ov[j];                  // Q(-M)
      }
      tfma(aE, xv, yv);
      tfma(aO, xv, yw);
    }
    // low-order part, read before the barrier (in-place write after)
    float eT[4][4], oT[4][4];
#pragma unroll
    for (int i = 0; i < 4; ++i) {
      const f32x4 msr = ld4(&b0[(r0 + i) * 64 + c0]);
      const f32x4 m2r = ld4(&b1[(r0 + i) * 64 + c0]);
      const f32x4 m3r = ld4(&b2[(r0 + i) * 64 + c0]);
      const f32x4 m4r = ld4(&b3[(r0 + i) * 64 + c0]);
#pragma unroll
      for (int j = 0; j < 4; ++j) {
        const float d = (r0 + i == c0 + j) ? 1.0f : 0.0f;
        const float even = d + fmaf(C4, m4r[j], C2 * m2r[j]);
        const float odd = fmaf(C3, m3r[j], C1 * msr[j]);
        eT[i][j] = aE[i][j] + even + odd;
        oT[i][j] = aO[i][j] + even - odd;
      }
    }
    __syncthreads();  // all reads of b0..b3 done
#pragma unroll
    for (int i = 0; i < 4; ++i) {
      f32x4 ve, vo;
#pragma unroll
      for (int j = 0; j < 4; ++j) {
        ve[j] = eT[i][j];
        vo[j] = oT[i][j];
      }
      st4(&b0[(r0 + i) * 64 + c0], ve);  // E
      st4(&b1[(r0 + i) * 64 + c0], vo);  // Et = E^T
    }
  }
  __syncthreads();

  // ---- P5 (fused): E2 = E*E = prim(Et,E);  E2t = (E2)^T = prim(E,Et) ----
  {
    float aA[4][4], aB[4][4];
    tzero(aA);
    tzero(aB);
#pragma unroll 2
    for (int k = 0; k < 64; ++k) {
      const f32x4 etr = ld4(&b1[k * 64 + r0]);
      const f32x4 er = ld4(&b0[k * 64 + r0]);
      const f32x4 ec = ld4(&b0[k * 64 + c0]);
      const f32x4 etc2 = ld4(&b1[k * 64 + c0]);
      tfma(aA, etr, ec);
      tfma(aB, er, etc2);
    }
#pragma unroll
    for (int i = 0; i < 4; ++i) {
      f32x4 va, vb;
#pragma unroll
      for (int j = 0; j < 4; ++j) {
        va[j] = aA[i][j];
        vb[j] = aB[i][j];
      }
      st4(&b2[(r0 + i) * 64 + c0], va);  // E2
      st4(&b3[(r0 + i) * 64 + c0], vb);  // E2t
    }
  }
  __syncthreads();

  // ---- P6: E4 = E2*E2 = prim(E2t,E2) -> global (row-major, coalesced chunks) ----
  {
    float a[4][4];
    tzero(a);
#pragma unroll 4
    for (int k = 0; k < 64; ++k) tfma(a, ld4(&b3[k * 64 + r0]), ld4(&b2[k * 64 + c0]));
#pragma unroll
    for (int i = 0; i < 4; ++i) {
      f32x4 v;
#pragma unroll
      for (int j = 0; j < 4; ++j) v[j] = a[i][j];
      st4(&dst[(r0 + i) * 64 + c0], v);
    }
  }
}

// Fused outputs (unchanged from the verified version). Blocks [0, NPOS): maps for
// position n (8 heads x 16 KB). Blocks [NPOS, NPOS + 64*64): steps 32x32 tiles.
__global__ __launch_bounds__(256) void outputs_kernel(const float* __restrict__ powers,
                                                      const int* __restrict__ pw, int L,
                                                      float* __restrict__ out_maps,
                                                      float* __restrict__ out_steps) {
  const int t = threadIdx.x;
  if (blockIdx.x < NPOS) {
    const int n = blockIdx.x;
    const int* row = pw + (size_t)n * L;  // wave-uniform -> scalar loads
    const bool sos = (row[0] == -1);
    int c = 0;
    for (int s = 0; s < L; ++s) {
      const int w = row[s];
      c += (w >= 0 && w < 2) ? 1 : 0;
    }
#pragma unroll
    for (int h = 0; h < NHEADS; ++h) {
      const float* src = sos ? (powers + (size_t)88 * 4096)
                             : (powers + (size_t)(c * NHEADS + h) * 4096);
      const f32x4* s4 = reinterpret_cast<const f32x4*>(src);
      f32x4* d4 = reinterpret_cast<f32x4*>(out_maps + ((size_t)n * NHEADS + h) * 4096);
#pragma unroll
      for (int i = 0; i < 4; ++i) {
        const f32x4 v = s4[t + 256 * i];
        __builtin_nontemporal_store(v, &d4[t + 256 * i]);
      }
    }
  } else {
    const int tb = blockIdx.x - NPOS;
    const int bi = (tb >> 6) * 32, bj = (tb & 63) * 32;
    __shared__ int pwi[32][16];
    __shared__ int pwj[32][16];
    __shared__ int li[32], lj[32];
    if (t < 32) {
      const int* row = pw + (size_t)(bi + t) * L;
      int len = 0;
      for (int s = 0; s < L; ++s) {
        const int w = row[s];
        pwi[t][s] = w;
        len += (w != PADW);
      }
      li[t] = len;
    } else if (t < 64) {
      const int r = t - 32;
      const int* row = pw + (size_t)(bj + r) * L;
      int len = 0;
      for (int s = 0; s < L; ++s) {
        const int w = row[s];
        pwj[r][s] = w;
        len += (w != PADW);
      }
      lj[r] = len;
    }
    __syncthreads();
    const int tx = t & 31, ty0 = t >> 5;
#pragma unroll
    for (int m = 0; m < 4; ++m) {
      const int ty = ty0 + 8 * m;
      int prefix = 1, common = 0;
      for (int s = 0; s < L; ++s) {
        const int wi = pwi[ty][s], wj = pwj[tx][s];
        prefix &= (wi == wj);
        common += prefix & (int)(wi != PADW) & (int)(wj != PADW);
      }
      const float steps = (float)(max(li[ty], lj[tx]) - common);
      __builtin_nontemporal_store(steps, &out_steps[(size_t)(bi + ty) * NPOS + (bj + tx)]);
    }
  }
}

extern "C" void kernel_launch(void* const* d_in, const int* in_sizes, int n_in,
                              void* d_out, int out_size, void* d_ws, size_t ws_size,
                              hipStream_t stream) {
  const float* U = (const float*)d_in[0];
  const int* pw = (const int*)d_in[1];
  const int L = in_sizes[1] / NPOS;  // = 10

  float* powers = (float*)d_ws;  // 89 * 4096 floats: [k*8+h] for k<=10, slot 88 = sos

  float* out_maps = (float*)d_out;
  float* out_steps = out_maps + (size_t)NPOS * NHEADS * 4096;

  hipLaunchKernelGGL(prologue_kernel, dim3(89), dim3(256), 0, stream, U, powers);
  hipLaunchKernelGGL(outputs_kernel, dim3(NPOS + 64 * 64), dim3(256), 0, stream,
                     powers, pw, L, out_maps, out_steps);
}

// Round 2
// 298.163 us; speedup vs baseline: 1.0564x; 1.0564x over previous
//
#include <hip/hip_runtime.h>

#define DIM 64
#define NHEADS 8
#define NPOS 2048
#define PADW 3

typedef float f32x4 __attribute__((ext_vector_type(4)));

// Taylor coefficients 1/j!
#define C1 1.0f
#define C2 0.5f
#define C3 (1.0f / 6.0f)
#define C4 (1.0f / 24.0f)
#define C5 (1.0f / 120.0f)
#define C6 (1.0f / 720.0f)
#define C7 (1.0f / 5040.0f)
#define C8 (1.0f / 40320.0f)

__device__ __forceinline__ f32x4 ld4(const float* p) { return *reinterpret_cast<const f32x4*>(p); }
__device__ __forceinline__ void st4(float* p, f32x4 v) { *reinterpret_cast<f32x4*>(p) = v; }
__device__ __forceinline__ void tzero(float (&a)[4][4]) {
#pragma unroll
  for (int i = 0; i < 4; ++i)
#pragma unroll
    for (int j = 0; j < 4; ++j) a[i][j] = 0.0f;
}
__device__ __forceinline__ void tfma(float (&a)[4][4], const f32x4 x, const f32x4 y) {
#pragma unroll
  for (int i = 0; i < 4; ++i)
#pragma unroll
    for (int j = 0; j < 4; ++j) a[i][j] = fmaf(x[i], y[j], a[i][j]);
}

// Prologue (unchanged, verified R1): powers[b] = expm(k*A), A = (U_m - U_m^T)/64,
// k = b>>3, head m = 8+(b&7); slot 88 = sos = expm(A_16). Antisymmetry: transposes
// of all polynomial intermediates are sign flips; prim(X,Y) = X^T Y reads both
// operands along rows (conflict-free ds_read_b128).
__global__ __launch_bounds__(256, 1) void prologue_kernel(const float* __restrict__ U,
                                                          float* __restrict__ powers) {
  __shared__ __align__(16) float b0[4096];
  __shared__ __align__(16) float b1[4096];
  __shared__ __align__(16) float b2[4096];
  __shared__ __align__(16) float b3[4096];
  const int t = threadIdx.x;
  const int b = blockIdx.x;
  const bool sos = (b == 88);
  const int kp = sos ? 1 : (b >> 3);
  float* __restrict__ dst = powers + (size_t)b * 4096;

  if (kp == 0) {  // B^0 = I
    for (int i = t; i < 4096; i += 256) dst[i] = ((i >> 6) == (i & 63)) ? 1.0f : 0.0f;
    return;
  }

  const int m = sos ? 16 : (NHEADS + (b & 7));
  const float* __restrict__ Um = U + (size_t)m * 4096;
  const float scale = (float)kp * (1.0f / 256.0f);  // k/4 * 1/64

  const int r0 = ((t >> 4) & 15) << 2;  // tile rows r0..r0+3
  const int c0 = (t & 15) << 2;         // tile cols c0..c0+3

  // ---- P0: Ms = scale * (U - U^T) ----
  {
    f32x4 ur[4], uc[4];
#pragma unroll
    for (int i = 0; i < 4; ++i) ur[i] = ld4(&Um[(r0 + i) * 64 + c0]);
#pragma unroll
    for (int j = 0; j < 4; ++j) uc[j] = ld4(&Um[(c0 + j) * 64 + r0]);
#pragma unroll
    for (int i = 0; i < 4; ++i) {
      f32x4 v;
#pragma unroll
      for (int j = 0; j < 4; ++j) v[j] = scale * (ur[i][j] - uc[j][i]);
      st4(&b0[(r0 + i) * 64 + c0], v);
    }
  }
  __syncthreads();

  // ---- P1: M2 = -(Ms^T Ms) ----
  {
    float a[4][4];
    tzero(a);
#pragma unroll 4
    for (int k = 0; k < 64; ++k) tfma(a, ld4(&b0[k * 64 + r0]), ld4(&b0[k * 64 + c0]));
#pragma unroll
    for (int i = 0; i < 4; ++i) {
      f32x4 v;
#pragma unroll
      for (int j = 0; j < 4; ++j) v[j] = -a[i][j];
      st4(&b1[(r0 + i) * 64 + c0], v);
    }
  }
  __syncthreads();

  // ---- P23 (fused): M3 = -(Ms^T M2), M4 = (M2^T M2) ----
  {
    float a3[4][4], a4[4][4];
    tzero(a3);
    tzero(a4);
#pragma unroll 4
    for (int k = 0; k < 64; ++k) {
      const f32x4 msr = ld4(&b0[k * 64 + r0]);
      const f32x4 m2r = ld4(&b1[k * 64 + r0]);
      const f32x4 m2c = ld4(&b1[k * 64 + c0]);
      tfma(a3, msr, m2c);
      tfma(a4, m2r, m2c);
    }
#pragma unroll
    for (int i = 0; i < 4; ++i) {
      f32x4 v3, v4;
#pragma unroll
      for (int j = 0; j < 4; ++j) {
        v3[j] = -a3[i][j];
        v4[j] = a4[i][j];
      }
      st4(&b2[(r0 + i) * 64 + c0], v3);
      st4(&b3[(r0 + i) * 64 + c0], v4);
    }
  }
  __syncthreads();

  // ---- P4 (dual): E = low(M) + M^4*Q(M); Et = E(-M) = E^T ----
  {
    float aE[4][4], aO[4][4];
    tzero(aE);
    tzero(aO);
#pragma unroll 2
    for (int k = 0; k < 64; ++k) {
      const f32x4 xv = ld4(&b3[k * 64 + r0]);  // M4 row (M4^T = M4)
      const f32x4 msv = ld4(&b0[k * 64 + c0]);
      const f32x4 m2v = ld4(&b1[k * 64 + c0]);
      const f32x4 m3v = ld4(&b2[k * 64 + c0]);
      const f32x4 m4v = ld4(&b3[k * 64 + c0]);
      f32x4 ev, ov, yv, yw;
#pragma unroll
      for (int j = 0; j < 4; ++j) {
        ev[j] = fmaf(C8, m4v[j], C6 * m2v[j]);
        ov[j] = fmaf(C7, m3v[j], C5 * msv[j]);
        yv[j] = ev[j] + ov[j];
        yw[j] = ev[j] - ov[j];
      }
      tfma(aE, xv, yv);
      tfma(aO, xv, yw);
    }
    float eT[4][4], oT[4][4];
#pragma unroll
    for (int i = 0; i < 4; ++i) {
      const f32x4 msr = ld4(&b0[(r0 + i) * 64 + c0]);
      const f32x4 m2r = ld4(&b1[(r0 + i) * 64 + c0]);
      const f32x4 m3r = ld4(&b2[(r0 + i) * 64 + c0]);
      const f32x4 m4r = ld4(&b3[(r0 + i) * 64 + c0]);
#pragma unroll
      for (int j = 0; j < 4; ++j) {
        const float d = (r0 + i == c0 + j) ? 1.0f : 0.0f;
        const float even = d + fmaf(C4, m4r[j], C2 * m2r[j]);
        const float odd = fmaf(C3, m3r[j], C1 * msr[j]);
        eT[i][j] = aE[i][j] + even + odd;
        oT[i][j] = aO[i][j] + even - odd;
      }
    }
    __syncthreads();  // all reads of b0..b3 done
#pragma unroll
    for (int i = 0; i < 4; ++i) {
      f32x4 ve, vo;
#pragma unroll
      for (int j = 0; j < 4; ++j) {
        ve[j] = eT[i][j];
        vo[j] = oT[i][j];
      }
      st4(&b0[(r0 + i) * 64 + c0], ve);  // E
      st4(&b1[(r0 + i) * 64 + c0], vo);  // Et
    }
  }
  __syncthreads();

  // ---- P5 (fused): E2 = prim(Et,E); E2t = prim(E,Et) ----
  {
    float aA[4][4], aB[4][4];
    tzero(aA);
    tzero(aB);
#pragma unroll 2
    for (int k = 0; k < 64; ++k) {
      const f32x4 etr = ld4(&b1[k * 64 + r0]);
      const f32x4 er = ld4(&b0[k * 64 + r0]);
      const f32x4 ec = ld4(&b0[k * 64 + c0]);
      const f32x4 etc2 = ld4(&b1[k * 64 + c0]);
      tfma(aA, etr, ec);
      tfma(aB, er, etc2);
    }
#pragma unroll
    for (int i = 0; i < 4; ++i) {
      f32x4 va, vb;
#pragma unroll
      for (int j = 0; j < 4; ++j) {
        va[j] = aA[i][j];
        vb[j] = aB[i][j];
      }
      st4(&b2[(r0 + i) * 64 + c0], va);  // E2
      st4(&b3[(r0 + i) * 64 + c0], vb);  // E2t
    }
  }
  __syncthreads();

  // ---- P6: E4 = prim(E2t,E2) -> global ----
  {
    float a[4][4];
    tzero(a);
#pragma unroll 4
    for (int k = 0; k < 64; ++k) tfma(a, ld4(&b3[k * 64 + r0]), ld4(&b2[k * 64 + c0]));
#pragma unroll
    for (int i = 0; i < 4; ++i) {
      f32x4 v;
#pragma unroll
      for (int j = 0; j < 4; ++j) v[j] = a[i][j];
      st4(&dst[(r0 + i) * 64 + c0], v);
    }
  }
}

// Outputs v2. Blocks [0, 4096): steps 32x32 tiles via PACKED path compare
// (path words in {-1,0,1,2}, PAD=3 strictly suffix, L=10 -> 3 bits/word packs a
// row into 30 bits; common = min(ctz(xi^xj)/3, li, lj); steps = max(li,lj)-common).
// Kills the old 16-way pwj bank conflict + ~80 LDS reads per thread.
// Blocks [4096, 4096+NPOS): maps copy, PLAIN f32x4 stores (NT dropped: poison
// fill hits 6.4 TB/s with the normal store path).
__global__ __launch_bounds__(256) void outputs_kernel(const float* __restrict__ powers,
                                                      const int* __restrict__ pw, int L,
                                                      float* __restrict__ out_maps,
                                                      float* __restrict__ out_steps) {
  const int t = threadIdx.x;
  if (blockIdx.x < 64 * 64) {
    const int tb = blockIdx.x;
    const int bi = (tb >> 6) * 32, bj = (tb & 63) * 32;
    __shared__ unsigned long long pki[32], pkj[32];
    __shared__ int li[32], lj[32];
    if (t < 64) {
      const int r = (t < 32) ? (bi + t) : (bj + (t - 32));
      const int* row = pw + (size_t)r * L;
      int len = 0;
      unsigned long long packed = 0ull;
      for (int s = 0; s < L; ++s) {
        const int w = row[s];
        len += (w != PADW) ? 1 : 0;
        packed |= (unsigned long long)(unsigned)(w + 1) << (3 * s);  // w+1 in [0,4]
      }
      if (t < 32) {
        pki[t] = packed;
        li[t] = len;
      } else {
        pkj[t - 32] = packed;
        lj[t - 32] = len;
      }
    }
    __syncthreads();
    const int tx = t & 31, ty0 = t >> 5;
    const unsigned long long xj = pkj[tx];
    const int lenj = lj[tx];
#pragma unroll
    for (int m = 0; m < 4; ++m) {
      const int ty = ty0 + 8 * m;
      const unsigned long long x = pki[ty] ^ xj;
      const int leni = li[ty];
      const int p = x ? (__builtin_ctzll(x) / 3) : L;
      const int common = min(p, min(leni, lenj));
      const float steps = (float)(max(leni, lenj) - common);
      out_steps[(size_t)(bi + ty) * NPOS + (bj + tx)] = steps;
    }
  } else {
    const int n = blockIdx.x - 64 * 64;
    const int* row = pw + (size_t)n * L;  // wave-uniform -> scalar loads
    const bool sos = (row[0] == -1);
    int c = 0;
    for (int s = 0; s < L; ++s) {
      const int w = row[s];
      c += (w >= 0 && w < 2) ? 1 : 0;
    }
#pragma unroll
    for (int h = 0; h < NHEADS; ++h) {
      const float* src = sos ? (powers + (size_t)88 * 4096)
                             : (powers + (size_t)(c * NHEADS + h) * 4096);
      const f32x4* s4 = reinterpret_cast<const f32x4*>(src);
      f32x4* d4 = reinterpret_cast<f32x4*>(out_maps + ((size_t)n * NHEADS + h) * 4096);
#pragma unroll
      for (int i = 0; i < 4; ++i) d4[t + 256 * i] = s4[t + 256 * i];
    }
  }
}

extern "C" void kernel_launch(void* const* d_in, const int* in_sizes, int n_in,
                              void* d_out, int out_size, void* d_ws, size_t ws_size,
                              hipStream_t stream) {
  const float* U = (const float*)d_in[0];
  const int* pw = (const int*)d_in[1];
  const int L = in_sizes[1] / NPOS;  // = 10

  float* powers = (float*)d_ws;  // 89 * 4096 floats: [k*8+h] for k<=10, slot 88 = sos

  float* out_maps = (float*)d_out;
  float* out_steps = out_maps + (size_t)NPOS * NHEADS * 4096;

  hipLaunchKernelGGL(prologue_kernel, dim3(89), dim3(256), 0, stream, U, powers);
  hipLaunchKernelGGL(outputs_kernel, dim3(64 * 64 + NPOS), dim3(256), 0, stream,
                     powers, pw, L, out_maps, out_steps);
}